// Round 5
// baseline (402.120 us; speedup 1.0000x reference)
//
#include <hip/hip_runtime.h>

#define LOG2E 1.4426950408889634f
#define LN2   0.6931471805599453f

constexpr int BB = 4096;
constexpr int S  = 512;
constexpr int NT = 9;
constexpr int TD = 11;

// ---------------------------------------------------------------------------
// K1: per-row length L from mask (prefix mask), build compacted worklist of
// live (row, seg, lim) units. seg covers transitions t in [64s+1, 64s+64],
// lim = # live transitions in the segment (1..64).
// ---------------------------------------------------------------------------
__global__ __launch_bounds__(256) void k1_len_list(
    const int* __restrict__ mask,
    int* __restrict__ cnt, int* __restrict__ Ld, int* __restrict__ list)
{
    const int tid = threadIdx.x, w = tid >> 6, l = tid & 63;
    const int row = blockIdx.x * 4 + w;
    const int* mrow = mask + row * S;
    int4 a = ((const int4*)mrow)[l];
    int4 b = ((const int4*)mrow)[64 + l];
    int c = a.x + a.y + a.z + a.w + b.x + b.y + b.z + b.w;
    #pragma unroll
    for (int d = 1; d < 64; d <<= 1) c += __shfl_xor(c, d);
    if (l == 0) {
        Ld[row] = c;
        int ntr = c - 1;                  // transitions t = 1..L-1
        int ns  = (ntr + 63) >> 6;
        if (ns > 0) {
            int base = atomicAdd(cnt, ns);
            for (int s = 0; s < ns; ++s) {
                int lim = ntr - (s << 6); if (lim > 64) lim = 64;
                list[base + s] = row | (s << 12) | ((lim - 1) << 15);
            }
        }
    }
}

// ---------------------------------------------------------------------------
// K2: per live unit (row,seg): evolve the 9 basis rows of the segment's
// 9x9 transfer-matrix product, one basis row per lane, fully in-lane
// (81 fma/step, no cross-lane). Lane c of unit u: global lane = u*9+c.
// Folds the real-path score (emission gather + mid transitions) in the
// same pass so emissions are streamed exactly once.
// Rescale by exact powers of 2 every 8 steps (bit trick, no rcp error).
// ---------------------------------------------------------------------------
__global__ __launch_bounds__(256) void k2_segments(
    const float* __restrict__ em, const int* __restrict__ tags,
    const float* __restrict__ trans,
    const int* __restrict__ cnt, const int* __restrict__ list,
    float* __restrict__ realp, int* __restrict__ Ebuf, float* __restrict__ Mbuf)
{
    const int lam = blockIdx.x * 256 + threadIdx.x;
    const unsigned uu = (unsigned)lam / 9u;
    const int c = lam - (int)uu * 9;
    if ((int)uu >= *cnt) return;
    const int e   = list[uu];
    const int row = e & 4095, seg = (e >> 12) & 7, lim = ((e >> 15) & 63) + 1;
    const int t0  = seg * 64 + 1;
    const float* emr = em + (size_t)row * (S * NT);
    const int*   tgr = tags + row * S;

    float W[9][9];                         // W[i][j] = 2^(T[i][j]*log2e)
    #pragma unroll
    for (int i = 0; i < 9; ++i)
        #pragma unroll
        for (int j = 0; j < 9; ++j)
            W[i][j] = exp2f(trans[i * TD + j] * LOG2E);

    float v[9];
    #pragma unroll
    for (int j = 0; j < 9; ++j) v[j] = (j == c) ? 1.f : 0.f;
    int   eacc = 0;
    float racc = 0.f;

    // software-pipeline: step i's em/tag/trans/emsel prefetched at step i-1
    float emc[9], emn[9];
    #pragma unroll
    for (int j = 0; j < 9; ++j) emc[j] = emr[t0 * NT + j];
    int   tgp = tgr[t0 - 1];
    int   tgc = tgr[t0];
    float trc = trans[tgp * TD + tgc];
    float esc = emr[t0 * NT + tgc];        // em[t0][tag_t0] (L1-hot line)
    int   tl1 = t0 + 1; if (tl1 > 511) tl1 = 511;
    int   tgn = tgr[tl1];

    for (int o = 0; o < 8; ++o) {
        #pragma unroll
        for (int iu = 0; iu < 8; ++iu) {
            const int i  = o * 8 + iu;
            int tn  = t0 + i + 1; int tln  = tn  > 511 ? 511 : tn;
            int tn2 = t0 + i + 2; int tln2 = tn2 > 511 ? 511 : tn2;
            // prefetch for step i+1
            #pragma unroll
            for (int j = 0; j < 9; ++j) emn[j] = emr[tln * NT + j];
            float esn = emr[tln * NT + tgn];
            float trn = trans[tgc * TD + tgn];
            int   tgn2 = tgr[tln2];
            // compute step i
            float x[9];
            #pragma unroll
            for (int j = 0; j < 9; ++j) x[j] = exp2f(emc[j] * LOG2E);
            float nv[9];
            #pragma unroll
            for (int j = 0; j < 9; ++j) {
                float d = v[0] * W[0][j];
                #pragma unroll
                for (int ii = 1; ii < 9; ++ii) d = fmaf(v[ii], W[ii][j], d);
                nv[j] = d * x[j];
            }
            const bool mk = (i < lim);
            #pragma unroll
            for (int j = 0; j < 9; ++j) v[j] = mk ? nv[j] : v[j];
            racc += mk ? (esc + trc) : 0.f;
            // shift pipeline
            #pragma unroll
            for (int j = 0; j < 9; ++j) emc[j] = emn[j];
            tgc = tgn; tgn = tgn2; trc = trn; esc = esn;
        }
        // exact pow2 rescale (v > 0 after >=1 step; lim >= 1 always)
        float mx = v[0];
        #pragma unroll
        for (int j = 1; j < 9; ++j) mx = fmaxf(mx, v[j]);
        unsigned eb = __float_as_uint(mx) & 0xFF800000u;
        eacc += (int)(eb >> 23) - 127;
        float sc = __uint_as_float((254u << 23) - eb);   // exact 2^-E
        #pragma unroll
        for (int j = 0; j < 9; ++j) v[j] *= sc;
    }

    const size_t sc9 = (size_t)seg * 9 + c;
    #pragma unroll
    for (int j = 0; j < 9; ++j) Mbuf[(sc9 * 9 + j) * 4096 + row] = v[j];
    Ebuf[sc9 * 4096 + row] = eacc;
    if (c == 0) realp[seg * 4096 + row] = racc;
}

// ---------------------------------------------------------------------------
// K3: one lane per row (64 consecutive rows per wave -> coalesced M loads).
// alpha0 -> chain <=8 segment matrices (ldexp-scaled matvec) -> total,
// assemble real score, per-block partial sums.
// ---------------------------------------------------------------------------
__global__ __launch_bounds__(64) void k3_combine(
    const float* __restrict__ em, const int* __restrict__ tags,
    const float* __restrict__ trans,
    const int* __restrict__ Ld, const float* __restrict__ realp,
    const int* __restrict__ Ebuf, const float* __restrict__ Mbuf,
    float* __restrict__ partV, float* __restrict__ partN)
{
    const int row = blockIdx.x * 64 + threadIdx.x;
    const float* emr = em + (size_t)row * (S * NT);
    const int L = Ld[row];
    const int ntr = L - 1, nseg = (ntr + 63) >> 6;
    const int tg0 = tags[row * S];
    const int tgl = tags[row * S + L - 1];
    float real = emr[tg0] + trans[9 * TD + tg0] + trans[tgl * TD + 10];

    float u[9], a0[9];
    #pragma unroll
    for (int j = 0; j < 9; ++j) a0[j] = (trans[9 * TD + j] + emr[j]) * LOG2E;
    float m0 = a0[0];
    #pragma unroll
    for (int j = 1; j < 9; ++j) m0 = fmaxf(m0, a0[j]);
    #pragma unroll
    for (int j = 0; j < 9; ++j) u[j] = exp2f(a0[j] - m0);
    float acc = m0;                                   // running log2 scale

    for (int s = 0; s < 8; ++s) {                     // fixed trip, masked
        const bool live = s < nseg;
        float rp = realp[s * 4096 + row];
        real += live ? rp : 0.f;
        int E[9];
        #pragma unroll
        for (int c = 0; c < 9; ++c) E[c] = Ebuf[((size_t)s * 9 + c) * 4096 + row];
        int Em = E[0];
        #pragma unroll
        for (int c = 1; c < 9; ++c) Em = max(Em, E[c]);
        float w[9];
        #pragma unroll
        for (int c = 0; c < 9; ++c) w[c] = ldexpf(u[c], E[c] - Em);
        float nu[9];
        #pragma unroll
        for (int j = 0; j < 9; ++j) nu[j] = 0.f;
        #pragma unroll
        for (int c = 0; c < 9; ++c) {
            #pragma unroll
            for (int j = 0; j < 9; ++j)
                nu[j] = fmaf(w[c], Mbuf[(((size_t)s * 9 + c) * 9 + j) * 4096 + row], nu[j]);
        }
        float mx = nu[0];
        #pragma unroll
        for (int j = 1; j < 9; ++j) mx = fmaxf(mx, nu[j]);
        unsigned eb = __float_as_uint(mx) & 0xFF800000u;
        float scn = __uint_as_float((254u << 23) - eb);
        float acc2 = acc + (float)Em + (float)((int)(eb >> 23) - 127);
        #pragma unroll
        for (int j = 0; j < 9; ++j) u[j] = live ? nu[j] * scn : u[j];
        acc = live ? acc2 : acc;
    }

    float dot = 0.f;
    #pragma unroll
    for (int j = 0; j < 9; ++j)
        dot = fmaf(u[j], exp2f(trans[j * TD + 10] * LOG2E), dot);
    float total = (acc + log2f(dot)) * LN2;

    float contrib = total - real;
    float nn = (float)L;
    #pragma unroll
    for (int d = 1; d < 64; d <<= 1) {
        contrib += __shfl_xor(contrib, d);
        nn      += __shfl_xor(nn, d);
    }
    if (threadIdx.x == 0) { partV[blockIdx.x] = contrib; partN[blockIdx.x] = nn; }
}

__global__ __launch_bounds__(64) void k4_final(
    const float* __restrict__ pV, const float* __restrict__ pN,
    float* __restrict__ out)
{
    const int l = threadIdx.x;
    float v = pV[l], n = pN[l];
    #pragma unroll
    for (int d = 1; d < 64; d <<= 1) { v += __shfl_xor(v, d); n += __shfl_xor(n, d); }
    if (l == 0) out[0] = v / n;
}

extern "C" void kernel_launch(void* const* d_in, const int* in_sizes, int n_in,
                              void* d_out, int out_size, void* d_ws, size_t ws_size,
                              hipStream_t stream) {
    const float* em    = (const float*)d_in[0];
    const int*   mask  = (const int*)d_in[1];
    const int*   tags  = (const int*)d_in[2];
    const float* trans = (const float*)d_in[3];

    // workspace carve (floats/ints, 4B each), total ~12 MB
    int*   cnt   = (int*)d_ws;                  // [1] (+pad to 64)
    int*   Ld    = cnt + 64;                    // [4096]
    int*   list  = Ld + 4096;                   // [32768]
    float* realp = (float*)(list + 32768);      // [8*4096]
    int*   Ebuf  = (int*)(realp + 8 * 4096);    // [8*9*4096]
    float* Mbuf  = (float*)(Ebuf + 8 * 9 * 4096); // [8*9*9*4096] = 10.6MB
    float* partV = Mbuf + (size_t)8 * 9 * 9 * 4096; // [64]
    float* partN = partV + 64;                  // [64]

    hipMemsetAsync(cnt, 0, sizeof(int), stream);
    k1_len_list<<<BB / 4, 256, 0, stream>>>(mask, cnt, Ld, list);
    k2_segments<<<(32768 * 9) / 256, 256, 0, stream>>>(em, tags, trans,
                                                       cnt, list, realp, Ebuf, Mbuf);
    k3_combine<<<BB / 64, 64, 0, stream>>>(em, tags, trans, Ld, realp,
                                           Ebuf, Mbuf, partV, partN);
    k4_final<<<1, 64, 0, stream>>>(partV, partN, (float*)d_out);
}

// Round 7
// 394.367 us; speedup vs baseline: 1.0197x; 1.0197x over previous
//
#include <hip/hip_runtime.h>

#define LOG2E 1.4426950408889634f
#define LN2   0.6931471805599453f

constexpr int BB = 4096;
constexpr int S  = 512;
constexpr int NT = 9;
constexpr int TD = 11;

// ---------------------------------------------------------------------------
// K1: per-row length L from mask (prefix mask), build compacted worklist of
// live (row, seg, lim) units. seg covers transitions t in [64s+1, 64s+64].
// ---------------------------------------------------------------------------
__global__ __launch_bounds__(256) void k1_len_list(
    const int* __restrict__ mask,
    int* __restrict__ cnt, int* __restrict__ Ld, int* __restrict__ list)
{
    const int tid = threadIdx.x, w = tid >> 6, l = tid & 63;
    const int row = blockIdx.x * 4 + w;
    const int* mrow = mask + row * S;
    int4 a = ((const int4*)mrow)[l];
    int4 b = ((const int4*)mrow)[64 + l];
    int c = a.x + a.y + a.z + a.w + b.x + b.y + b.z + b.w;
    #pragma unroll
    for (int d = 1; d < 64; d <<= 1) c += __shfl_xor(c, d);
    if (l == 0) {
        Ld[row] = c;
        int ntr = c - 1;                  // transitions t = 1..L-1
        int ns  = (ntr + 63) >> 6;
        if (ns > 0) {
            int base = atomicAdd(cnt, ns);
            for (int s = 0; s < ns; ++s) {
                int lim = ntr - (s << 6); if (lim > 64) lim = 64;
                list[base + s] = row | (s << 12) | ((lim - 1) << 15);
            }
        }
    }
}

// ---------------------------------------------------------------------------
// K2: per live unit (row,seg): evolve the 9 basis rows of the segment's
// 9x9 transfer-matrix product, one basis row per lane, fully in-lane.
// Folds the real-path score in the same pass. 2-step-deep software pipeline
// on the em/tags/trans streams. Exact pow2 rescale every 8 steps.
// ---------------------------------------------------------------------------
__global__ __launch_bounds__(256) void k2_segments(
    const float* __restrict__ em, const int* __restrict__ tags,
    const float* __restrict__ trans,
    const int* __restrict__ cnt, const int* __restrict__ list,
    float* __restrict__ realp, int* __restrict__ Ebuf, float* __restrict__ Mbuf)
{
    const int lam = blockIdx.x * 256 + threadIdx.x;
    const unsigned uu = (unsigned)lam / 9u;
    const int c = lam - (int)uu * 9;
    if ((int)uu >= *cnt) return;
    const int e   = list[uu];
    const int row = e & 4095, seg = (e >> 12) & 7, lim = ((e >> 15) & 63) + 1;
    const int t0  = seg * 64 + 1;
    const float* emr = em + (size_t)row * (S * NT);
    const int*   tgr = tags + row * S;

    float W[9][9];                         // W[i][j] = 2^(T[i][j]*log2e)
    #pragma unroll
    for (int i = 0; i < 9; ++i)
        #pragma unroll
        for (int j = 0; j < 9; ++j)
            W[i][j] = exp2f(trans[i * TD + j] * LOG2E);

    float v[9];
    #pragma unroll
    for (int j = 0; j < 9; ++j) v[j] = (j == c) ? 1.f : 0.f;
    int   eacc = 0;
    float racc = 0.f;

    // 2-deep software pipeline on em vector + tag/trans/em-gather scalars
    float emc[9], emn[9], emn2[9];
    int t1c = t0 + 1; if (t1c > 511) t1c = 511;
    int t2c = t0 + 2; if (t2c > 511) t2c = 511;
    #pragma unroll
    for (int j = 0; j < 9; ++j) { emc[j] = emr[t0 * NT + j]; emn[j] = emr[t1c * NT + j]; }
    int   tgp  = tgr[t0 - 1];
    int   tgc  = tgr[t0];
    int   tgn  = tgr[t1c];
    int   tgn2 = tgr[t2c];
    float trc = trans[tgp * TD + tgc];
    float trn = trans[tgc * TD + tgn];
    float esc = emr[t0 * NT + tgc];
    float esn = emr[t1c * NT + tgn];

    for (int o = 0; o < 8; ++o) {
        #pragma unroll
        for (int iu = 0; iu < 8; ++iu) {
            const int i  = o * 8 + iu;
            int tn2 = t0 + i + 2; int tln2 = tn2 > 511 ? 511 : tn2;
            int tn3 = t0 + i + 3; int tln3 = tn3 > 511 ? 511 : tn3;
            // prefetch for step i+2
            #pragma unroll
            for (int j = 0; j < 9; ++j) emn2[j] = emr[tln2 * NT + j];
            float esn2 = emr[tln2 * NT + tgn2];
            float trn2 = trans[tgn * TD + tgn2];
            int   tgn3 = tgr[tln3];
            // compute step i (consumes emc/esc/trc)
            float x[9];
            #pragma unroll
            for (int j = 0; j < 9; ++j) x[j] = exp2f(emc[j] * LOG2E);
            float nv[9];
            #pragma unroll
            for (int j = 0; j < 9; ++j) {
                float d = v[0] * W[0][j];
                #pragma unroll
                for (int ii = 1; ii < 9; ++ii) d = fmaf(v[ii], W[ii][j], d);
                nv[j] = d * x[j];
            }
            const bool mk = (i < lim);
            #pragma unroll
            for (int j = 0; j < 9; ++j) v[j] = mk ? nv[j] : v[j];
            racc += mk ? (esc + trc) : 0.f;
            // shift pipeline
            #pragma unroll
            for (int j = 0; j < 9; ++j) { emc[j] = emn[j]; emn[j] = emn2[j]; }
            esc = esn; esn = esn2;
            trc = trn; trn = trn2;
            tgn = tgn2; tgn2 = tgn3;
        }
        // exact pow2 rescale (v > 0 after >=1 step; lim >= 1 always)
        float mx = v[0];
        #pragma unroll
        for (int j = 1; j < 9; ++j) mx = fmaxf(mx, v[j]);
        unsigned eb = __float_as_uint(mx) & 0xFF800000u;
        eacc += (int)(eb >> 23) - 127;
        float sc = __uint_as_float((254u << 23) - eb);   // exact 2^-E
        #pragma unroll
        for (int j = 0; j < 9; ++j) v[j] *= sc;
    }

    const size_t sc9 = (size_t)seg * 9 + c;
    #pragma unroll
    for (int j = 0; j < 9; ++j) Mbuf[(sc9 * 9 + j) * 4096 + row] = v[j];
    Ebuf[sc9 * 4096 + row] = eacc;
    if (c == 0) realp[seg * 4096 + row] = racc;
}

// ---------------------------------------------------------------------------
// K3: one lane per row (64 consecutive rows per wave -> coalesced M loads).
// Segment chain FULLY UNROLLED (static addresses -> compiler pipelines the
// next segment's 90 loads under this segment's matvec). Exact pow2 scaling
// via exponent bit-trick (no ldexpf).
// ---------------------------------------------------------------------------
__global__ __launch_bounds__(64) void k3_combine(
    const float* __restrict__ em, const int* __restrict__ tags,
    const float* __restrict__ trans,
    const int* __restrict__ Ld, const float* __restrict__ realp,
    const int* __restrict__ Ebuf, const float* __restrict__ Mbuf,
    float* __restrict__ partV, float* __restrict__ partN)
{
    const int row = blockIdx.x * 64 + threadIdx.x;
    const float* emr = em + (size_t)row * (S * NT);
    const int L = Ld[row];
    const int ntr = L - 1, nseg = (ntr + 63) >> 6;
    const int tg0 = tags[row * S];
    const int tgl = tags[row * S + L - 1];
    float real = emr[tg0] + trans[9 * TD + tg0] + trans[tgl * TD + 10];

    float u[9], a0[9];
    #pragma unroll
    for (int j = 0; j < 9; ++j) a0[j] = (trans[9 * TD + j] + emr[j]) * LOG2E;
    float m0 = a0[0];
    #pragma unroll
    for (int j = 1; j < 9; ++j) m0 = fmaxf(m0, a0[j]);
    #pragma unroll
    for (int j = 0; j < 9; ++j) u[j] = exp2f(a0[j] - m0);
    float acc = m0;                                   // running log2 scale

    #pragma unroll
    for (int s = 0; s < 8; ++s) {                     // fully unrolled, masked
        const bool live = s < nseg;
        float rp = realp[s * 4096 + row];
        real += live ? rp : 0.f;
        int E[9];
        #pragma unroll
        for (int c = 0; c < 9; ++c) E[c] = Ebuf[((size_t)s * 9 + c) * 4096 + row];
        int Em = E[0];
        #pragma unroll
        for (int c = 1; c < 9; ++c) Em = max(Em, E[c]);
        float w[9];
        #pragma unroll
        for (int c = 0; c < 9; ++c) {
            int d = E[c] - Em;                        // <= 0
            float sc = (d >= -126) ? __uint_as_float((unsigned)(127 + d) << 23) : 0.f;
            w[c] = u[c] * sc;                         // exact pow2 scale
        }
        float nu[9];
        #pragma unroll
        for (int j = 0; j < 9; ++j) nu[j] = 0.f;
        #pragma unroll
        for (int c = 0; c < 9; ++c) {
            #pragma unroll
            for (int j = 0; j < 9; ++j)
                nu[j] = fmaf(w[c], Mbuf[(((size_t)s * 9 + c) * 9 + j) * 4096 + row], nu[j]);
        }
        float mx = nu[0];
        #pragma unroll
        for (int j = 1; j < 9; ++j) mx = fmaxf(mx, nu[j]);
        unsigned eb = __float_as_uint(mx) & 0xFF800000u;
        float scn = __uint_as_float((254u << 23) - eb);
        float acc2 = acc + (float)Em + (float)((int)(eb >> 23) - 127);
        #pragma unroll
        for (int j = 0; j < 9; ++j) u[j] = live ? nu[j] * scn : u[j];
        acc = live ? acc2 : acc;
    }

    float dot = 0.f;
    #pragma unroll
    for (int j = 0; j < 9; ++j)
        dot = fmaf(u[j], exp2f(trans[j * TD + 10] * LOG2E), dot);
    float total = (acc + log2f(dot)) * LN2;

    float contrib = total - real;
    float nn = (float)L;
    #pragma unroll
    for (int d = 1; d < 64; d <<= 1) {
        contrib += __shfl_xor(contrib, d);
        nn      += __shfl_xor(nn, d);
    }
    if (threadIdx.x == 0) { partV[blockIdx.x] = contrib; partN[blockIdx.x] = nn; }
}

__global__ __launch_bounds__(64) void k4_final(
    const float* __restrict__ pV, const float* __restrict__ pN,
    float* __restrict__ out)
{
    const int l = threadIdx.x;
    float v = pV[l], n = pN[l];
    #pragma unroll
    for (int d = 1; d < 64; d <<= 1) { v += __shfl_xor(v, d); n += __shfl_xor(n, d); }
    if (l == 0) out[0] = v / n;
}

extern "C" void kernel_launch(void* const* d_in, const int* in_sizes, int n_in,
                              void* d_out, int out_size, void* d_ws, size_t ws_size,
                              hipStream_t stream) {
    const float* em    = (const float*)d_in[0];
    const int*   mask  = (const int*)d_in[1];
    const int*   tags  = (const int*)d_in[2];
    const float* trans = (const float*)d_in[3];

    // workspace carve (floats/ints, 4B each), total ~12 MB
    int*   cnt   = (int*)d_ws;                  // [1] (+pad to 64)
    int*   Ld    = cnt + 64;                    // [4096]
    int*   list  = Ld + 4096;                   // [32768]
    float* realp = (float*)(list + 32768);      // [8*4096]
    int*   Ebuf  = (int*)(realp + 8 * 4096);    // [8*9*4096]
    float* Mbuf  = (float*)(Ebuf + 8 * 9 * 4096); // [8*9*9*4096] = 10.6MB
    float* partV = Mbuf + (size_t)8 * 9 * 9 * 4096; // [64]
    float* partN = partV + 64;                  // [64]

    hipMemsetAsync(cnt, 0, sizeof(int), stream);
    k1_len_list<<<BB / 4, 256, 0, stream>>>(mask, cnt, Ld, list);
    k2_segments<<<(32768 * 9) / 256, 256, 0, stream>>>(em, tags, trans,
                                                       cnt, list, realp, Ebuf, Mbuf);
    k3_combine<<<BB / 64, 64, 0, stream>>>(em, tags, trans, Ld, realp,
                                           Ebuf, Mbuf, partV, partN);
    k4_final<<<1, 64, 0, stream>>>(partV, partN, (float*)d_out);
}

// Round 8
// 280.869 us; speedup vs baseline: 1.4317x; 1.4041x over previous
//
#include <hip/hip_runtime.h>

#define LOG2E 1.4426950408889634f
#define LN2   0.6931471805599453f

constexpr int BB = 4096;
constexpr int S  = 512;
constexpr int NT = 9;
constexpr int TD = 11;
constexpr int NSEG = 8;
constexpr int MTOT = NSEG * 81 * BB;   // 2654208 Mbuf elements
constexpr int ETOT = NSEG * 9 * BB;    // 294912 Ebuf elements

// exact 2^d for d <= 0 (clamped to 0 below denormal range)
__device__ __forceinline__ float pow2neg(int d) {
    return (d >= -126) ? __uint_as_float((unsigned)(127 + d) << 23) : 0.f;
}

// ---------------------------------------------------------------------------
// K1: per-row length L, compacted worklist of live (row,seg,lim) units,
// and identity-init of all 8 Mbuf slots + zero Ebuf (grid-stride tail).
// ---------------------------------------------------------------------------
__global__ __launch_bounds__(256) void k1_prep(
    const int* __restrict__ mask,
    int* __restrict__ cnt, int* __restrict__ Ld, int* __restrict__ list,
    float* __restrict__ Mbuf, int* __restrict__ Ebuf)
{
    const int tid = threadIdx.x, w = tid >> 6, l = tid & 63;
    const int row = blockIdx.x * 4 + w;
    const int* mrow = mask + row * S;
    int4 a = ((const int4*)mrow)[l];
    int4 b = ((const int4*)mrow)[64 + l];
    int c = a.x + a.y + a.z + a.w + b.x + b.y + b.z + b.w;
    #pragma unroll
    for (int d = 1; d < 64; d <<= 1) c += __shfl_xor(c, d);
    if (l == 0) {
        Ld[row] = c;
        int ntr = c - 1;                      // transitions t = 1..L-1
        int ns  = (ntr + 63) >> 6;
        if (ns > 0) {
            int base = atomicAdd(cnt, ns);
            for (int s = 0; s < ns; ++s) {
                int lim = ntr - (s << 6); if (lim > 64) lim = 64;
                list[base + s] = row | (s << 12) | ((lim - 1) << 15);
            }
        }
    }
    // identity init (value (c==j)), layout Mbuf[((s*9+c)*9+j)*4096 + row]
    const int gtid = blockIdx.x * 256 + tid;
    for (int u = gtid; u < MTOT; u += 1024 * 256) {
        int scj = u >> 12;
        int j = scj % 9, cc = (scj / 9) % 9;
        Mbuf[u] = (cc == j) ? 1.f : 0.f;
    }
    for (int u = gtid; u < ETOT; u += 1024 * 256) Ebuf[u] = 0;
}

// ---------------------------------------------------------------------------
// K_real: full real-path score per row (64 lanes strided over t).
// Covers emissions for t in [0,L), transitions t-1->t for t in [1,L),
// plus start/end transitions.
// ---------------------------------------------------------------------------
__global__ __launch_bounds__(256, 1) void k_real(
    const float* __restrict__ em, const int* __restrict__ tags,
    const float* __restrict__ trans, const int* __restrict__ Ld,
    float* __restrict__ realR)
{
    const int tid = threadIdx.x, w = tid >> 6, l = tid & 63;
    const int row = blockIdx.x * 4 + w;
    const float* emr = em + (size_t)row * (S * NT);
    const int*   tgr = tags + row * S;
    const int L = Ld[row];
    float sum = 0.f;
    int prev = 0;
    #pragma unroll
    for (int it = 0; it < 8; ++it) {
        int t  = it * 64 + l;
        int tg = tgr[t];
        float ev = emr[t * NT + tg];
        int tgp = __shfl_up(tg, 1);
        if (l == 0) tgp = prev;
        prev = __shfl(tg, 63);
        float tr = (t > 0) ? trans[tgp * TD + tg] : 0.f;
        if (t < L) sum += ev + tr;
    }
    #pragma unroll
    for (int d = 1; d < 64; d <<= 1) sum += __shfl_xor(sum, d);
    if (l == 0) {
        int tg0 = tgr[0], tgl = tgr[L - 1];
        realR[row] = sum + trans[9 * TD + tg0] + trans[tgl * TD + 10];
    }
}

// ---------------------------------------------------------------------------
// K2: per live unit (row,seg): 9x9 transfer-matrix product over <=64 steps,
// one basis row per lane. Emissions streamed as 18 x float2 per 4-step chunk
// (8B-aligned: base index 9*(t0+1) is even), explicit double buffer.
// Exact pow2 rescale every 8 steps.
// ---------------------------------------------------------------------------
__global__ __launch_bounds__(256, 2) void k2_segments(
    const float* __restrict__ em, const float* __restrict__ trans,
    const int* __restrict__ cnt, const int* __restrict__ list,
    int* __restrict__ Ebuf, float* __restrict__ Mbuf)
{
    const int lam = blockIdx.x * 256 + threadIdx.x;
    const unsigned uu = (unsigned)lam / 9u;
    const int c = lam - (int)uu * 9;
    if ((int)uu >= *cnt) return;
    const int e   = list[uu];
    const int row = e & 4095, seg = (e >> 12) & 7, lim = ((e >> 15) & 63) + 1;
    const int t0  = seg * 64 + 1;
    const float* emr = em + (size_t)row * (S * NT);

    float W[9][9];                         // W[i][j] = 2^(T[i][j]*log2e)
    #pragma unroll
    for (int i = 0; i < 9; ++i)
        #pragma unroll
        for (int j = 0; j < 9; ++j)
            W[i][j] = exp2f(trans[i * TD + j] * LOG2E);

    // prologue: step i=0 (t=t0), always live (lim >= 1)
    float v[9];
    #pragma unroll
    for (int j = 0; j < 9; ++j)
        v[j] = W[c][j] * exp2f(emr[t0 * NT + j] * LOG2E);
    int eacc = 0;

    // chunk c covers steps i = 4c+1 .. 4c+4 ; floats [f0+36c, f0+36c+35]
    const int f0 = NT * (t0 + 1);          // even -> 8B aligned
    float2 cur[18], nxt[18];
    #pragma unroll
    for (int q = 0; q < 18; ++q) {
        int off = f0 + 2 * q; off = min(off, NT * S - 2);
        cur[q] = *(const float2*)(emr + off);
    }

    #pragma unroll
    for (int ch = 0; ch < 16; ++ch) {
        if (ch < 15) {
            #pragma unroll
            for (int q = 0; q < 18; ++q) {
                int off = f0 + 36 * (ch + 1) + 2 * q; off = min(off, NT * S - 2);
                nxt[q] = *(const float2*)(emr + off);
            }
        }
        #pragma unroll
        for (int s = 0; s < 4; ++s) {
            const int i = 4 * ch + 1 + s;
            if (i <= 63) {
                float nv[9];
                #pragma unroll
                for (int j = 0; j < 9; ++j) {
                    float d = v[0] * W[0][j];
                    #pragma unroll
                    for (int ii = 1; ii < 9; ++ii) d = fmaf(v[ii], W[ii][j], d);
                    const int u = 9 * s + j;                  // local float idx
                    float ef = (u & 1) ? cur[u >> 1].y : cur[u >> 1].x;
                    nv[j] = d * exp2f(ef * LOG2E);
                }
                const bool mk = (i < lim);
                #pragma unroll
                for (int j = 0; j < 9; ++j) v[j] = mk ? nv[j] : v[j];
            }
        }
        if (ch & 1) {                       // rescale every 8 steps
            float mx = v[0];
            #pragma unroll
            for (int j = 1; j < 9; ++j) mx = fmaxf(mx, v[j]);
            unsigned eb = __float_as_uint(mx) & 0xFF800000u;
            eacc += (int)(eb >> 23) - 127;
            float sc = __uint_as_float((254u << 23) - eb);   // exact 2^-E
            #pragma unroll
            for (int j = 0; j < 9; ++j) v[j] *= sc;
        }
        if (ch < 15) {
            #pragma unroll
            for (int q = 0; q < 18; ++q) cur[q] = nxt[q];
        }
    }

    const int sc9 = seg * 9 + c;
    #pragma unroll
    for (int j = 0; j < 9; ++j) Mbuf[(size_t)(sc9 * 9 + j) * 4096 + row] = v[j];
    Ebuf[(size_t)sc9 * 4096 + row] = eacc;
}

// ---------------------------------------------------------------------------
// Kmul: one tree level. Lane (row, pair p, matrix-row i) computes row i of
// A_true * B_true, A = slot p*2*st, B = A + st, result -> A's slot (in place:
// each lane reads then writes only its own row of A; B slots untouched).
// Liveness is a prefix, so (identity-left, live-right) never occurs.
// ---------------------------------------------------------------------------
__global__ __launch_bounds__(256, 2) void kmul(
    float* Mbuf, int* Ebuf, int st, int P)
{
    const int g = blockIdx.x * 256 + threadIdx.x;   // 4096*9*P total
    const int row = g & 4095;
    const int r = g >> 12;                          // 0..9P-1
    const int i = r % 9, p = r / 9;
    const int sa = p * 2 * st, sb = sa + st;

    int EAi = Ebuf[(size_t)(sa * 9 + i) * 4096 + row];
    int EB[9];
    #pragma unroll
    for (int k = 0; k < 9; ++k) EB[k] = Ebuf[(size_t)(sb * 9 + k) * 4096 + row];
    float A[9];
    #pragma unroll
    for (int k = 0; k < 9; ++k) A[k] = Mbuf[(size_t)((sa * 9 + i) * 9 + k) * 4096 + row];
    float B[9][9];
    #pragma unroll
    for (int k = 0; k < 9; ++k)
        #pragma unroll
        for (int j = 0; j < 9; ++j)
            B[k][j] = Mbuf[(size_t)((sb * 9 + k) * 9 + j) * 4096 + row];

    int Em = EB[0];
    #pragma unroll
    for (int k = 1; k < 9; ++k) Em = max(Em, EB[k]);
    float as_[9];
    #pragma unroll
    for (int k = 0; k < 9; ++k) as_[k] = A[k] * pow2neg(EB[k] - Em);
    float acc[9];
    #pragma unroll
    for (int j = 0; j < 9; ++j) acc[j] = 0.f;
    #pragma unroll
    for (int k = 0; k < 9; ++k)
        #pragma unroll
        for (int j = 0; j < 9; ++j)
            acc[j] = fmaf(as_[k], B[k][j], acc[j]);

    float mx = acc[0];
    #pragma unroll
    for (int j = 1; j < 9; ++j) mx = fmaxf(mx, acc[j]);
    unsigned eb = __float_as_uint(mx) & 0xFF800000u;
    float scn = __uint_as_float((254u << 23) - eb);
    int Eout = EAi + Em + (int)(eb >> 23) - 127;
    #pragma unroll
    for (int j = 0; j < 9; ++j)
        Mbuf[(size_t)((sa * 9 + i) * 9 + j) * 4096 + row] = acc[j] * scn;
    Ebuf[(size_t)(sa * 9 + i) * 4096 + row] = Eout;
}

// ---------------------------------------------------------------------------
// K3_final: one lane per row. alpha0 -> single matvec with slot-0 matrix ->
// total; contrib = total - realR; per-block partials.
// ---------------------------------------------------------------------------
__global__ __launch_bounds__(64, 1) void k3_final(
    const float* __restrict__ em, const float* __restrict__ trans,
    const int* __restrict__ Ld, const float* __restrict__ realR,
    const int* __restrict__ Ebuf, const float* __restrict__ Mbuf,
    float* __restrict__ partV, float* __restrict__ partN)
{
    const int row = blockIdx.x * 64 + threadIdx.x;
    const float* emr = em + (size_t)row * (S * NT);
    const int L = Ld[row];

    float u[9];
    float m0;
    {
        float a0[9];
        #pragma unroll
        for (int j = 0; j < 9; ++j) a0[j] = (trans[9 * TD + j] + emr[j]) * LOG2E;
        m0 = a0[0];
        #pragma unroll
        for (int j = 1; j < 9; ++j) m0 = fmaxf(m0, a0[j]);
        #pragma unroll
        for (int j = 0; j < 9; ++j) u[j] = exp2f(a0[j] - m0);
    }

    int E[9];
    #pragma unroll
    for (int c = 0; c < 9; ++c) E[c] = Ebuf[(size_t)c * 4096 + row];
    int Em = E[0];
    #pragma unroll
    for (int c = 1; c < 9; ++c) Em = max(Em, E[c]);
    float w[9];
    #pragma unroll
    for (int c = 0; c < 9; ++c) w[c] = u[c] * pow2neg(E[c] - Em);
    float nu[9];
    #pragma unroll
    for (int j = 0; j < 9; ++j) nu[j] = 0.f;
    #pragma unroll
    for (int c = 0; c < 9; ++c)
        #pragma unroll
        for (int j = 0; j < 9; ++j)
            nu[j] = fmaf(w[c], Mbuf[(size_t)(c * 9 + j) * 4096 + row], nu[j]);

    float dot = 0.f;
    #pragma unroll
    for (int j = 0; j < 9; ++j)
        dot = fmaf(nu[j], exp2f(trans[j * TD + 10] * LOG2E), dot);
    float total = (m0 + (float)Em + log2f(dot)) * LN2;

    float contrib = total - realR[row];
    float nn = (float)L;
    #pragma unroll
    for (int d = 1; d < 64; d <<= 1) {
        contrib += __shfl_xor(contrib, d);
        nn      += __shfl_xor(nn, d);
    }
    if (threadIdx.x == 0) { partV[blockIdx.x] = contrib; partN[blockIdx.x] = nn; }
}

__global__ __launch_bounds__(64) void k4_final(
    const float* __restrict__ pV, const float* __restrict__ pN,
    float* __restrict__ out)
{
    const int l = threadIdx.x;
    float v = pV[l], n = pN[l];
    #pragma unroll
    for (int d = 1; d < 64; d <<= 1) { v += __shfl_xor(v, d); n += __shfl_xor(n, d); }
    if (l == 0) out[0] = v / n;
}

extern "C" void kernel_launch(void* const* d_in, const int* in_sizes, int n_in,
                              void* d_out, int out_size, void* d_ws, size_t ws_size,
                              hipStream_t stream) {
    const float* em    = (const float*)d_in[0];
    const int*   mask  = (const int*)d_in[1];
    const int*   tags  = (const int*)d_in[2];
    const float* trans = (const float*)d_in[3];

    // workspace carve (4B units), total ~12.1 MB
    int*   cnt   = (int*)d_ws;                    // [64]
    int*   Ld    = cnt + 64;                      // [4096]
    int*   list  = Ld + 4096;                     // [32768]
    float* realR = (float*)(list + 32768);        // [4096]
    int*   Ebuf  = (int*)(realR + 4096);          // [8*9*4096]
    float* Mbuf  = (float*)(Ebuf + ETOT);         // [8*81*4096]
    float* partV = Mbuf + MTOT;                   // [64]
    float* partN = partV + 64;                    // [64]

    hipMemsetAsync(cnt, 0, sizeof(int), stream);
    k1_prep<<<BB / 4, 256, 0, stream>>>(mask, cnt, Ld, list, Mbuf, Ebuf);
    k_real <<<BB / 4, 256, 0, stream>>>(em, tags, trans, Ld, realR);
    k2_segments<<<(32768 * 9) / 256, 256, 0, stream>>>(em, trans, cnt, list, Ebuf, Mbuf);
    kmul<<<576, 256, 0, stream>>>(Mbuf, Ebuf, 1, 4);
    kmul<<<288, 256, 0, stream>>>(Mbuf, Ebuf, 2, 2);
    kmul<<<144, 256, 0, stream>>>(Mbuf, Ebuf, 4, 1);
    k3_final<<<BB / 64, 64, 0, stream>>>(em, trans, Ld, realR, Ebuf, Mbuf, partV, partN);
    k4_final<<<1, 64, 0, stream>>>(partV, partN, (float*)d_out);
}